// Round 1
// baseline (182.137 us; speedup 1.0000x reference)
//
#include <hip/hip_runtime.h>

// QuantLinear: out[8,11008] = x[8,4096] @ W[11008,4096]^T
// W: packed[f/2] int32 holds one byte; low nibble = even k, high = odd k; q-8, *scales[f/32].
//
// Design: 1 wave (64 threads) per block. Each wave: 8 output rows, one K-half (2048).
//   Lane owns 8 consecutive k per 512-k tile (4 tiles per half).
//   Weights: 8x dwordx4 per tile (coalesced 1 KiB/wave-instr) — the 90 MB HBM stream.
//   x: 2x float4 per m per tile from global (L2-resident 128 KB), reused across 8 rows.
//   Epilogue: 6-step shfl_xor merge tree -> lane l holds total for (r=l>>3, m=l&7),
//   atomicAdd (split-K=2) into memset-zeroed d_out.

#define OUT_F 11008
#define IN_F  4096

__global__ __launch_bounds__(64) void qlin_kernel(
    const float* __restrict__ x,
    const int*   __restrict__ packed,
    const float* __restrict__ scales,
    float*       __restrict__ out)
{
    const int lane = threadIdx.x;          // 0..63
    const int b    = blockIdx.x;           // 0..2751
    const int o0   = (b >> 1) * 8;         // 8 output rows per wave
    const int k0   = (b & 1) * 2048;       // K-half

    float acc[64];                         // acc[r*8 + m]
#pragma unroll
    for (int i = 0; i < 64; ++i) acc[i] = 0.f;

#pragma unroll
    for (int t = 0; t < 4; ++t) {          // 4 tiles of 512 k per half
        const int kb = k0 + t * 512 + lane * 8;   // lane's k base (8 consecutive k)

        int4 wq[8];
#pragma unroll
        for (int r = 0; r < 8; ++r)
            wq[r] = *(const int4*)(packed + (o0 + r) * 2048 + (kb >> 1));

        float sc[8], ns[8];
#pragma unroll
        for (int r = 0; r < 8; ++r) {
            const float s = scales[(o0 + r) * 128 + (kb >> 5)];  // lane's 8 k share one block
            sc[r] = s;
            ns[r] = -8.f * s;
        }

        // ---- half 0: k = kb..kb+3 (bytes wq.x, wq.y) ----
        {
            float w[8][4];
#pragma unroll
            for (int r = 0; r < 8; ++r) {
                const int p0 = wq[r].x, p1 = wq[r].y;
                w[r][0] = fmaf((float)(p0 & 15),        sc[r], ns[r]);
                w[r][1] = fmaf((float)((p0 >> 4) & 15), sc[r], ns[r]);
                w[r][2] = fmaf((float)(p1 & 15),        sc[r], ns[r]);
                w[r][3] = fmaf((float)((p1 >> 4) & 15), sc[r], ns[r]);
            }
#pragma unroll
            for (int m = 0; m < 8; ++m) {
                const float4 xa = *(const float4*)(x + m * IN_F + kb);
#pragma unroll
                for (int r = 0; r < 8; ++r) {
                    float a = acc[r * 8 + m];
                    a = fmaf(w[r][0], xa.x, a);
                    a = fmaf(w[r][1], xa.y, a);
                    a = fmaf(w[r][2], xa.z, a);
                    a = fmaf(w[r][3], xa.w, a);
                    acc[r * 8 + m] = a;
                }
            }
        }
        // ---- half 1: k = kb+4..kb+7 (bytes wq.z, wq.w) ----
        {
            float w[8][4];
#pragma unroll
            for (int r = 0; r < 8; ++r) {
                const int p0 = wq[r].z, p1 = wq[r].w;
                w[r][0] = fmaf((float)(p0 & 15),        sc[r], ns[r]);
                w[r][1] = fmaf((float)((p0 >> 4) & 15), sc[r], ns[r]);
                w[r][2] = fmaf((float)(p1 & 15),        sc[r], ns[r]);
                w[r][3] = fmaf((float)((p1 >> 4) & 15), sc[r], ns[r]);
            }
#pragma unroll
            for (int m = 0; m < 8; ++m) {
                const float4 xa = *(const float4*)(x + m * IN_F + kb + 4);
#pragma unroll
                for (int r = 0; r < 8; ++r) {
                    float a = acc[r * 8 + m];
                    a = fmaf(w[r][0], xa.x, a);
                    a = fmaf(w[r][1], xa.y, a);
                    a = fmaf(w[r][2], xa.z, a);
                    a = fmaf(w[r][3], xa.w, a);
                    acc[r * 8 + m] = a;
                }
            }
        }
    }

    // ---- cross-lane merge tree: after 6 steps lane l holds total of acc[l] ----
#pragma unroll
    for (int s = 0; s < 6; ++s) {
        const int bit = (lane >> s) & 1;
        const int n = 32 >> s;
#pragma unroll
        for (int j = 0; j < n; ++j) {
            const float u = bit ? acc[2 * j + 1] : acc[2 * j];
            const float v = bit ? acc[2 * j]     : acc[2 * j + 1];
            acc[j] = u + __shfl_xor(v, 1 << s, 64);
        }
    }

    const int m = lane & 7;   // acc index l = r*8 + m
    const int r = lane >> 3;
    atomicAdd(out + m * OUT_F + o0 + r, acc[0]);
}

extern "C" void kernel_launch(void* const* d_in, const int* in_sizes, int n_in,
                              void* d_out, int out_size, void* d_ws, size_t ws_size,
                              hipStream_t stream) {
    const float* x      = (const float*)d_in[0];
    const int*   packed = (const int*)  d_in[1];
    const float* scales = (const float*)d_in[2];
    float*       out    = (float*)d_out;

    // d_out is poisoned 0xAA before every launch; zero it for the split-K atomics.
    hipMemsetAsync(out, 0, (size_t)out_size * sizeof(float), stream);

    const int row_groups = OUT_F / 8;          // 1376
    dim3 grid(row_groups * 2), block(64);      // split-K = 2 -> 2752 blocks
    hipLaunchKernelGGL(qlin_kernel, grid, block, 0, stream,
                       x, packed, scales, out);
}

// Round 2
// 164.002 us; speedup vs baseline: 1.1106x; 1.1106x over previous
//
#include <hip/hip_runtime.h>

// QuantLinear: out[8,11008] = x[8,4096] @ W[11008,4096]^T
// packed[i] (int32) holds ONE byte: low nibble = weight 2i, high = weight 2i+1; (q-8)*scale[idx/32].
//
// R2 design: 256-thread WG (4 waves). WG owns 8 output rows, full K=4096.
//   Wave w: k-strip [w*1024, w*1024+1024), looped as 2 tiles of 512 k; lane owns 8 consecutive k.
//   Weight loads: dwordx4 (4 packed ints = 8 weights), fully coalesced per row.
//   x: float4 loads from L2/L3-resident 128 KB, reused across 8 rows in registers.
//   Epilogue: 6-step shfl_xor merge tree (lane l <- total for r=l>>3, m=l&7),
//   then 1 KB LDS reduction across the 4 waves, single coalition-free store. No atomics, no memset.

#define OUT_F 11008
#define IN_F  4096

__global__ __launch_bounds__(256) void qlin_kernel(
    const float* __restrict__ x,
    const int*   __restrict__ packed,
    const float* __restrict__ scales,
    float*       __restrict__ out)
{
    const int tid  = threadIdx.x;
    const int lane = tid & 63;
    const int wave = tid >> 6;             // 0..3 -> K strip
    const int o0   = blockIdx.x * 8;       // 8 output rows per WG

    float acc[64];                         // acc[r*8 + m]
#pragma unroll
    for (int i = 0; i < 64; ++i) acc[i] = 0.f;

#pragma unroll
    for (int t = 0; t < 2; ++t) {          // 2 tiles of 512 k per wave
        const int kb = wave * 1024 + t * 512 + lane * 8;  // lane's 8 consecutive k

        int4 wq[8];
#pragma unroll
        for (int r = 0; r < 8; ++r)
            wq[r] = *(const int4*)(packed + (o0 + r) * 2048 + (kb >> 1));

        float sc[8], ns[8];
#pragma unroll
        for (int r = 0; r < 8; ++r) {
            const float s = scales[(o0 + r) * 128 + (kb >> 5)];  // lane's 8 k share one q-block
            sc[r] = s;
            ns[r] = -8.f * s;
        }

        // ---- half 0: k = kb..kb+3 (packed ints wq.x, wq.y) ----
        {
            float w[8][4];
#pragma unroll
            for (int r = 0; r < 8; ++r) {
                const int p0 = wq[r].x, p1 = wq[r].y;
                w[r][0] = fmaf((float)(p0 & 15),        sc[r], ns[r]);
                w[r][1] = fmaf((float)((p0 >> 4) & 15), sc[r], ns[r]);
                w[r][2] = fmaf((float)(p1 & 15),        sc[r], ns[r]);
                w[r][3] = fmaf((float)((p1 >> 4) & 15), sc[r], ns[r]);
            }
#pragma unroll
            for (int m = 0; m < 8; ++m) {
                const float4 xa = *(const float4*)(x + m * IN_F + kb);
#pragma unroll
                for (int r = 0; r < 8; ++r) {
                    float a = acc[r * 8 + m];
                    a = fmaf(w[r][0], xa.x, a);
                    a = fmaf(w[r][1], xa.y, a);
                    a = fmaf(w[r][2], xa.z, a);
                    a = fmaf(w[r][3], xa.w, a);
                    acc[r * 8 + m] = a;
                }
            }
        }
        // ---- half 1: k = kb+4..kb+7 (packed ints wq.z, wq.w) ----
        {
            float w[8][4];
#pragma unroll
            for (int r = 0; r < 8; ++r) {
                const int p0 = wq[r].z, p1 = wq[r].w;
                w[r][0] = fmaf((float)(p0 & 15),        sc[r], ns[r]);
                w[r][1] = fmaf((float)((p0 >> 4) & 15), sc[r], ns[r]);
                w[r][2] = fmaf((float)(p1 & 15),        sc[r], ns[r]);
                w[r][3] = fmaf((float)((p1 >> 4) & 15), sc[r], ns[r]);
            }
#pragma unroll
            for (int m = 0; m < 8; ++m) {
                const float4 xa = *(const float4*)(x + m * IN_F + kb + 4);
#pragma unroll
                for (int r = 0; r < 8; ++r) {
                    float a = acc[r * 8 + m];
                    a = fmaf(w[r][0], xa.x, a);
                    a = fmaf(w[r][1], xa.y, a);
                    a = fmaf(w[r][2], xa.z, a);
                    a = fmaf(w[r][3], xa.w, a);
                    acc[r * 8 + m] = a;
                }
            }
        }
    }

    // ---- cross-lane merge tree: after 6 steps lane l holds wave-total of acc[l] ----
#pragma unroll
    for (int s = 0; s < 6; ++s) {
        const int bit = (lane >> s) & 1;
        const int n = 32 >> s;
#pragma unroll
        for (int j = 0; j < n; ++j) {
            const float u = bit ? acc[2 * j + 1] : acc[2 * j];
            const float v = bit ? acc[2 * j]     : acc[2 * j + 1];
            acc[j] = u + __shfl_xor(v, 1 << s, 64);
        }
    }

    // ---- cross-wave reduction in LDS (stride-1, conflict-free) ----
    __shared__ float red[256];
    red[wave * 64 + lane] = acc[0];
    __syncthreads();
    if (tid < 64) {
        const float s = red[lane] + red[64 + lane] + red[128 + lane] + red[192 + lane];
        const int m = lane & 7;            // acc index l = r*8 + m
        const int r = lane >> 3;
        out[m * OUT_F + o0 + r] = s;
    }
}

extern "C" void kernel_launch(void* const* d_in, const int* in_sizes, int n_in,
                              void* d_out, int out_size, void* d_ws, size_t ws_size,
                              hipStream_t stream) {
    const float* x      = (const float*)d_in[0];
    const int*   packed = (const int*)  d_in[1];
    const float* scales = (const float*)d_in[2];
    float*       out    = (float*)d_out;

    dim3 grid(OUT_F / 8), block(256);      // 1376 WGs x 4 waves
    hipLaunchKernelGGL(qlin_kernel, grid, block, 0, stream,
                       x, packed, scales, out);
}

// Round 3
// 157.785 us; speedup vs baseline: 1.1543x; 1.0394x over previous
//
#include <hip/hip_runtime.h>

// QuantLinear: out[8,11008] = x[8,4096] @ W[11008,4096]^T
// packed[i] (int32) holds ONE byte: low nibble = weight 2i, high = weight 2i+1; (q-8)*scale[idx/32].
//
// R3 design: latency-hiding via register-double-buffered weight prefetch + deeper grid.
//   Grid: 2752 WGs (split-K=2) x 256 threads = 11008 waves (43/CU queued).
//   WG: 8 output rows, one K-half (2048). Wave w: 512-k strip, as 4 tiles of 128 k.
//   Lane owns 2 consecutive k = ONE packed dword per row per tile (coalesced 256 B/instr).
//   Tile t+1 weight+scale loads issue before tile t compute -> misses stay outstanding.
//   x: float2 per (m,tile) from L1/L2-resident 128 KB, reused across 8 rows.
//   Epilogue: shfl_xor merge tree -> LDS cross-wave reduce -> atomicAdd (split-K), out memset to 0.

#define OUT_F 11008
#define IN_F  4096

__global__ __launch_bounds__(256) void qlin_kernel(
    const float* __restrict__ x,
    const int*   __restrict__ packed,
    const float* __restrict__ scales,
    float*       __restrict__ out)
{
    const int tid  = threadIdx.x;
    const int lane = tid & 63;
    const int wave = tid >> 6;
    const int b    = blockIdx.x;                  // 0..2751
    const int o0   = (b >> 1) * 8;                // 8 output rows
    const int k0   = (b & 1) * 2048 + wave * 512; // wave's 512-k strip (mult of 512)

    const int pbase = (k0 >> 1) + lane;           // packed dword offset in row; tile t adds t*64
    const int sbase = (k0 >> 5) + (lane >> 4);    // scale offset in row; tile t adds t*4

    float acc[64];                                // acc[r*8 + m]
#pragma unroll
    for (int i = 0; i < 64; ++i) acc[i] = 0.f;

    int   wq[2][8];
    float sc[2][8];

    // prefetch tile 0
#pragma unroll
    for (int r = 0; r < 8; ++r) {
        wq[0][r] = packed[(o0 + r) * 2048 + pbase];
        sc[0][r] = scales[(o0 + r) * 128 + sbase];
    }

#pragma unroll
    for (int t = 0; t < 4; ++t) {
        const int cur = t & 1, nxt = cur ^ 1;

        // issue tile t+1 loads before consuming tile t (keeps misses outstanding)
        if (t < 3) {
#pragma unroll
            for (int r = 0; r < 8; ++r) {
                wq[nxt][r] = packed[(o0 + r) * 2048 + pbase + (t + 1) * 64];
                sc[nxt][r] = scales[(o0 + r) * 128 + sbase + (t + 1) * 4];
            }
        }

        const int kb = k0 + t * 128 + lane * 2;   // lane's 2 k (one q-block)

        float w0[8], w1[8];
#pragma unroll
        for (int r = 0; r < 8; ++r) {
            const int   p  = wq[cur][r];
            const float s  = sc[cur][r];
            const float ns = -8.f * s;
            w0[r] = fmaf((float)(p & 15),        s, ns);  // even k
            w1[r] = fmaf((float)((p >> 4) & 15), s, ns);  // odd k
        }

#pragma unroll
        for (int m = 0; m < 8; ++m) {
            const float2 xa = *(const float2*)(x + m * IN_F + kb);
#pragma unroll
            for (int r = 0; r < 8; ++r) {
                acc[r * 8 + m] = fmaf(w0[r], xa.x, fmaf(w1[r], xa.y, acc[r * 8 + m]));
            }
        }
    }

    // ---- cross-lane merge tree: after 6 steps lane l holds wave-total of acc[l] ----
#pragma unroll
    for (int s = 0; s < 6; ++s) {
        const int bit = (lane >> s) & 1;
        const int n = 32 >> s;
#pragma unroll
        for (int j = 0; j < n; ++j) {
            const float u = bit ? acc[2 * j + 1] : acc[2 * j];
            const float v = bit ? acc[2 * j]     : acc[2 * j + 1];
            acc[j] = u + __shfl_xor(v, 1 << s, 64);
        }
    }

    // ---- cross-wave reduction in LDS, then split-K atomic finish ----
    __shared__ float red[256];
    red[wave * 64 + lane] = acc[0];
    __syncthreads();
    if (tid < 64) {
        const float s = red[lane] + red[64 + lane] + red[128 + lane] + red[192 + lane];
        const int m = lane & 7;                   // merged index l = r*8 + m
        const int r = lane >> 3;
        atomicAdd(out + m * OUT_F + o0 + r, s);
    }
}

extern "C" void kernel_launch(void* const* d_in, const int* in_sizes, int n_in,
                              void* d_out, int out_size, void* d_ws, size_t ws_size,
                              hipStream_t stream) {
    const float* x      = (const float*)d_in[0];
    const int*   packed = (const int*)  d_in[1];
    const float* scales = (const float*)d_in[2];
    float*       out    = (float*)d_out;

    // split-K atomics accumulate into out -> zero it first (async, graph-capturable)
    hipMemsetAsync(out, 0, (size_t)out_size * sizeof(float), stream);

    dim3 grid((OUT_F / 8) * 2), block(256);       // 2752 WGs x 4 waves = 11008 waves
    hipLaunchKernelGGL(qlin_kernel, grid, block, 0, stream,
                       x, packed, scales, out);
}